// Round 6
// baseline (117.084 us; speedup 1.0000x reference)
//
#include <hip/hip_runtime.h>
#include <hip/hip_bf16.h>
#include <math.h>

#define N_IMG 8192
#define GROUPS 16
#define EMB 1600
#define IPB 4

typedef __attribute__((ext_vector_type(8))) short short8;
typedef __attribute__((ext_vector_type(16))) float f32x16;
typedef __attribute__((ext_vector_type(4))) unsigned int u32x4;

// ws layout (bytes): gsum[25600 f32]@0 ; w2f[18432 bf16]@102400 ;
//                    w1f[512 bf16]@139264 ; v[1600 f32]@140288
#define WS_W2F 102400
#define WS_W1F 139264
#define WS_V   140288

__device__ __forceinline__ unsigned short bfc(float f) {
    return __builtin_bit_cast(unsigned short, __float2bfloat16(f));
}
__device__ __forceinline__ unsigned pk2(float a, float b) {
    return (unsigned)bfc(a) | ((unsigned)bfc(b) << 16);
}

// ---------------------------------------------------------------------------
// prep: zero gsum ; pack w2 frags ; pack w1 frags (k = 4r + c4 map; c4==3 or
// r==3 slots zero -> garbage image reads at those k are multiplied by 0) ;
// v = fc1w @ fc2w (fc1,fc2 both linear -> collapse to one 1600-vector)
// ---------------------------------------------------------------------------
__global__ __launch_bounds__(256) void prep(
        const float* __restrict__ w1, const float* __restrict__ w2,
        const float* __restrict__ fc1w, const float* __restrict__ fc2w,
        float* __restrict__ gsum, unsigned short* __restrict__ w1f,
        unsigned short* __restrict__ w2f, float* __restrict__ v)
{
    int gid = blockIdx.x * 256 + threadIdx.x;
    if (gid < 25600) { gsum[gid] = 0.f; return; }
    gid -= 25600;
    if (gid < 18432) {
        int j = gid & 7, kk = (gid >> 3) & 1, n = (gid >> 4) & 63, c = gid >> 10;
        int s = c >> 1, h = c & 1;
        int ci = 16 * h + 8 * kk + j;
        w2f[gid] = bfc(w2[(s * 32 + ci) * 64 + n]);
        return;
    }
    gid -= 18432;
    if (gid < 512) {
        int j = gid & 7, ll = gid >> 3;
        int k = 8 * (ll >> 5) + j;
        int r = k >> 2, c4 = k & 3, co = ll & 31;
        w1f[gid] = (r < 3 && c4 < 3) ? bfc(w1[(r * 3 + c4) * 32 + co])
                                     : (unsigned short)0;
        return;
    }
    gid -= 512;
    if (gid < 1600) {
        const float4* a = (const float4*)(fc1w + gid * 512);
        const float4* bq = (const float4*)fc2w;
        float s = 0.f;
        for (int q = 0; q < 128; ++q) {
            float4 av = a[q], bv = bq[q];
            s += av.x * bv.x + av.y * bv.y + av.z * bv.z + av.w * bv.w;
        }
        v[gid] = s;
    }
}

// ---------------------------------------------------------------------------
// Fused: 4 waves/block, IPB images, 32x32x16 MFMA both convs, quad-mapped M.
// conv1: dual shifted bf16 image copies, uniform (non-divergent) 2x
// ds_read2_b32 per tile. conv2: wave = 1 M-tile x BOTH N-halves (A-read
// feeds 2 MFMAs; bb[18][2] = 144 VGPR kept register-resident via
// waves_per_eu(2,2)). sp2 slot-XOR swizzle kills 4-way b128 conflicts.
// 1 raw s_barrier per image, lgkmcnt-only drain (prefetch stays in flight).
// ---------------------------------------------------------------------------
__global__ __launch_bounds__(256)
__attribute__((amdgpu_waves_per_eu(2, 2)))
void fused(
        const float* __restrict__ x,
        const unsigned short* __restrict__ w1f, const float* __restrict__ b1,
        const unsigned short* __restrict__ w2f, const float* __restrict__ b2,
        float* __restrict__ gsum)
{
    __shared__ __align__(16) unsigned short simgb[2][1568]; // [dbuf][copy0|copy1]
    __shared__ __align__(16) unsigned short sp2[2][5760];   // [dbuf][quad144][40ch swz]

    const int tid = threadIdx.x;
    const int wv = tid >> 6;
    const int l = tid & 63;
    const int l31 = l & 31, lh = l >> 5;

    // conv1 B-frag
    const short8 wb1 = *(const short8*)(w1f + l * 8);
    const float cb1 = b1[l31];

    // conv2 B-frags: both N-halves (144 VGPR, register-resident)
    short8 bb[18][2];
    #pragma unroll
    for (int c = 0; c < 18; ++c) {
        bb[c][0] = *(const short8*)(w2f + ((c * 64 + l31) * 2 + lh) * 8);
        bb[c][1] = *(const short8*)(w2f + ((c * 64 + 32 + l31) * 2 + lh) * 8);
    }
    const float cb20 = b2[l31], cb21 = b2[32 + l31];

    // conv2 fixed A base position for this wave's M-tile (mt = wv)
    int m2 = 32 * wv + l31; if (m2 > 99) m2 = 99;
    const int q2i = m2 >> 2, idx2 = m2 & 3;
    const int r2 = 2 * (q2i / 5) + (idx2 >> 1), c2 = 2 * (q2i % 5) + (idx2 & 1);
    const int posb = r2 * 12 + c2;

    float pa00 = 0.f, pa01 = 0.f, pa02 = 0.f, pa03 = 0.f;
    float pa10 = 0.f, pa11 = 0.f, pa12 = 0.f, pa13 = 0.f;

    const int imgbase = blockIdx.x * IPB;
    const float* xbase = x + (size_t)imgbase * 784;

    // prologue: pack image 0 into simgb[0] (copy0 + 1-px-shifted copy1)
    if (tid < 98) {
        const float4* xg = (const float4*)xbase;
        float4 A = xg[2 * tid], B = xg[2 * tid + 1];
        float sc = xbase[(8 * tid + 8 < 784) ? 8 * tid + 8 : 783];
        *(u32x4*)(&simgb[0][8 * tid]) =
            (u32x4){pk2(A.x, A.y), pk2(A.z, A.w), pk2(B.x, B.y), pk2(B.z, B.w)};
        *(u32x4*)(&simgb[0][784 + 8 * tid]) =
            (u32x4){pk2(A.y, A.z), pk2(A.w, B.x), pk2(B.y, B.z), pk2(B.w, sc)};
    }
    asm volatile("s_waitcnt lgkmcnt(0)" ::: "memory");
    __builtin_amdgcn_s_barrier();

    for (int ii = 0; ii < IPB; ++ii) {
        const int cur = ii & 1;
        const unsigned short* simgc = simgb[cur];
        unsigned short* sp2c = sp2[cur];

        // issue next-image global loads early (HBM latency hides under conv1)
        float4 A4, B4; float sc = 0.f;
        const bool pf = (ii + 1 < IPB) && (tid < 98);
        if (pf) {
            const float4* xn = (const float4*)(xbase + (ii + 1) * 784);
            A4 = xn[2 * tid]; B4 = xn[2 * tid + 1];
            sc = xbase[(ii + 1) * 784 + ((8 * tid + 8 < 784) ? 8 * tid + 8 : 783)];
        }

        // ---- conv1: tiles t = 4*t9 + wv, uniform read pattern all lanes ----
        #pragma unroll
        for (int t9 = 0; t9 < 5; ++t9) {
            const int t = 4 * t9 + wv;
            if (t < 18) {
                const int qd = 8 * t + (l31 >> 2);
                const int idx1 = l & 3;
                const int pr = qd / 12, pc = qd % 12;
                const int rr = 2 * pr + (idx1 >> 1), ccc = 2 * pc + (idx1 & 1);
                const int s = ccc & 1;
                // lh==1 lanes shift base +2 rows; their k=11..15 slots have
                // zero weights, so the extra dwords read are don't-care.
                const int halfoff = s * 784 + rr * 28 + (ccc - s) + 56 * lh;
                const unsigned* bp = (const unsigned*)((const char*)simgc + 2 * halfoff);
                const unsigned d0 = bp[0], d1 = bp[1], d2 = bp[14], d3 = bp[15];
                const short8 af = __builtin_bit_cast(short8, (u32x4){d0, d1, d2, d3});
                f32x16 cc;
                #pragma unroll
                for (int z = 0; z < 16; ++z) cc[z] = cb1;
                cc = __builtin_amdgcn_mfma_f32_32x32x16_bf16(af, wb1, cc, 0, 0, 0);
                const int key1 = t & 3;
                const int choff = (((l31 >> 3) ^ key1) << 3) + (l31 & 7);
                #pragma unroll
                for (int rq = 0; rq < 4; ++rq) {
                    float p = fmaxf(fmaxf(cc[4 * rq], cc[4 * rq + 1]),
                                    fmaxf(cc[4 * rq + 2], cc[4 * rq + 3]));
                    p = fmaxf(p, 0.f);
                    sp2c[(8 * t + 2 * rq + lh) * 40 + choff] = bfc(p);
                }
            }
        }

        // pack prefetched image into the other buffer
        if (pf) {
            unsigned short* dst = simgb[cur ^ 1];
            *(u32x4*)(&dst[8 * tid]) =
                (u32x4){pk2(A4.x, A4.y), pk2(A4.z, A4.w), pk2(B4.x, B4.y), pk2(B4.z, B4.w)};
            *(u32x4*)(&dst[784 + 8 * tid]) =
                (u32x4){pk2(A4.y, A4.z), pk2(A4.w, B4.x), pk2(B4.y, B4.z), pk2(B4.w, sc)};
        }
        asm volatile("s_waitcnt lgkmcnt(0)" ::: "memory");
        __builtin_amdgcn_s_barrier();

        // ---- conv2: 1 M-tile, both N-halves, 18 K-chunks, swizzled reads ----
        f32x16 acc0, acc1;
        #pragma unroll
        for (int z = 0; z < 16; ++z) { acc0[z] = cb20; acc1[z] = cb21; }
        __builtin_amdgcn_s_setprio(1);
        #pragma unroll
        for (int s = 0; s < 9; ++s) {
            const int posp = posb + (s / 3) * 12 + (s % 3);
            const int key = (posp >> 3) & 3;
            const char* base = (const char*)sp2c + posp * 80;
            const short8 af0 = *(const short8*)(base + ((lh ^ key) << 4));
            const short8 af1 = *(const short8*)(base + (((2 + lh) ^ key) << 4));
            acc0 = __builtin_amdgcn_mfma_f32_32x32x16_bf16(af0, bb[2 * s][0], acc0, 0, 0, 0);
            acc1 = __builtin_amdgcn_mfma_f32_32x32x16_bf16(af0, bb[2 * s][1], acc1, 0, 0, 0);
            acc0 = __builtin_amdgcn_mfma_f32_32x32x16_bf16(af1, bb[2 * s + 1][0], acc0, 0, 0, 0);
            acc1 = __builtin_amdgcn_mfma_f32_32x32x16_bf16(af1, bb[2 * s + 1][1], acc1, 0, 0, 0);
        }
        __builtin_amdgcn_s_setprio(0);
        {
            float p;
            p = fmaxf(fmaxf(acc0[0],  acc0[1]),  fmaxf(acc0[2],  acc0[3]));  pa00 += fmaxf(p, 0.f);
            p = fmaxf(fmaxf(acc0[4],  acc0[5]),  fmaxf(acc0[6],  acc0[7]));  pa01 += fmaxf(p, 0.f);
            p = fmaxf(fmaxf(acc0[8],  acc0[9]),  fmaxf(acc0[10], acc0[11])); pa02 += fmaxf(p, 0.f);
            p = fmaxf(fmaxf(acc0[12], acc0[13]), fmaxf(acc0[14], acc0[15])); pa03 += fmaxf(p, 0.f);
            p = fmaxf(fmaxf(acc1[0],  acc1[1]),  fmaxf(acc1[2],  acc1[3]));  pa10 += fmaxf(p, 0.f);
            p = fmaxf(fmaxf(acc1[4],  acc1[5]),  fmaxf(acc1[6],  acc1[7]));  pa11 += fmaxf(p, 0.f);
            p = fmaxf(fmaxf(acc1[8],  acc1[9]),  fmaxf(acc1[10], acc1[11])); pa12 += fmaxf(p, 0.f);
            p = fmaxf(fmaxf(acc1[12], acc1[13]), fmaxf(acc1[14], acc1[15])); pa13 += fmaxf(p, 0.f);
        }
    }

    // one atomic per (quad, channel) per block; wv==3 keeps only rq0/lh0 (q2==24)
    const int grp = imgbase >> 9;
    float* gs = gsum + grp * EMB;
    const float pa0[4] = {pa00, pa01, pa02, pa03};
    const float pa1[4] = {pa10, pa11, pa12, pa13};
    #pragma unroll
    for (int rq = 0; rq < 4; ++rq) {
        if (wv < 3 || (rq == 0 && lh == 0)) {
            const int q2 = 8 * wv + 2 * rq + lh;
            atomicAdd(&gs[q2 * 64 + l31],      pa0[rq]);
            atomicAdd(&gs[q2 * 64 + 32 + l31], pa1[rq]);
        }
    }
}

// mean/512 -> max over 16 groups -> dot v -> + fc1b.fc2w + fc2b -> sigmoid
__global__ __launch_bounds__(256) void head(
        const float* __restrict__ gsum, const float* __restrict__ v,
        const float* __restrict__ fc1b, const float* __restrict__ fc2w,
        const float* __restrict__ fc2b, float* __restrict__ out)
{
    __shared__ float sred[256];
    const int tid = threadIdx.x;
    float partial = 0.f;
    const float4* g4 = (const float4*)gsum;
    const float4* v4 = (const float4*)v;
    for (int i = tid; i < 400; i += 256) {
        float4 m = g4[i];
        #pragma unroll
        for (int gg = 1; gg < GROUPS; ++gg) {
            float4 t = g4[gg * 400 + i];
            m.x = fmaxf(m.x, t.x); m.y = fmaxf(m.y, t.y);
            m.z = fmaxf(m.z, t.z); m.w = fmaxf(m.w, t.w);
        }
        float4 vv = v4[i];
        partial += m.x * vv.x + m.y * vv.y + m.z * vv.z + m.w * vv.w;
    }
    partial *= (1.f / 512.f);
    partial += fc1b[tid] * fc2w[tid] + fc1b[tid + 256] * fc2w[tid + 256];
    sred[tid] = partial;
    __syncthreads();
    for (int s = 128; s > 0; s >>= 1) {
        if (tid < s) sred[tid] += sred[tid + s];
        __syncthreads();
    }
    if (tid == 0) out[0] = 1.f / (1.f + expf(-(sred[0] + fc2b[0])));
}

extern "C" void kernel_launch(void* const* d_in, const int* in_sizes, int n_in,
                              void* d_out, int out_size, void* d_ws, size_t ws_size,
                              hipStream_t stream)
{
    const float* x    = (const float*)d_in[0];
    const float* w1   = (const float*)d_in[1];
    const float* b1   = (const float*)d_in[2];
    const float* w2   = (const float*)d_in[3];
    const float* b2   = (const float*)d_in[4];
    const float* fc1w = (const float*)d_in[5];
    const float* fc1b = (const float*)d_in[6];
    const float* fc2w = (const float*)d_in[7];
    const float* fc2b = (const float*)d_in[8];

    float* gsum = (float*)d_ws;
    unsigned short* w2f = (unsigned short*)((char*)d_ws + WS_W2F);
    unsigned short* w1f = (unsigned short*)((char*)d_ws + WS_W1F);
    float* v = (float*)((char*)d_ws + WS_V);

    prep<<<181, 256, 0, stream>>>(w1, w2, fc1w, fc2w, gsum, w1f, w2f, v);
    fused<<<N_IMG / IPB, 256, 0, stream>>>(x, w1f, b1, w2f, b2, gsum);
    head<<<1, 256, 0, stream>>>(gsum, v, fc1b, fc2w, fc2b, (float*)d_out);
}

// Round 7
// 79.488 us; speedup vs baseline: 1.4730x; 1.4730x over previous
//
#include <hip/hip_runtime.h>
#include <hip/hip_bf16.h>
#include <math.h>

#define N_IMG 8192
#define GROUPS 16
#define EMB 1600
#define IPB 4

typedef __attribute__((ext_vector_type(8))) short short8;
typedef __attribute__((ext_vector_type(16))) float f32x16;
typedef __attribute__((ext_vector_type(4))) unsigned int u32x4;

// ws layout (bytes): gsum[25600 f32]@0 ; w2f[18432 bf16]@102400 ;
//                    w1f[512 bf16]@139264 ; v[1600 f32]@140288
#define WS_W2F 102400
#define WS_W1F 139264
#define WS_V   140288

__device__ __forceinline__ unsigned short bfc(float f) {
    return __builtin_bit_cast(unsigned short, __float2bfloat16(f));
}
__device__ __forceinline__ unsigned pk2(float a, float b) {
    return (unsigned)bfc(a) | ((unsigned)bfc(b) << 16);
}

// ---------------------------------------------------------------------------
// prep: zero gsum ; pack w2 frags ; pack w1 frags (k = 4r + c4 map; c4==3 or
// r==3 slots zero) ; v = fc1w @ fc2w (fc1,fc2 linear -> collapse)
// ---------------------------------------------------------------------------
__global__ __launch_bounds__(256) void prep(
        const float* __restrict__ w1, const float* __restrict__ w2,
        const float* __restrict__ fc1w, const float* __restrict__ fc2w,
        float* __restrict__ gsum, unsigned short* __restrict__ w1f,
        unsigned short* __restrict__ w2f, float* __restrict__ v)
{
    int gid = blockIdx.x * 256 + threadIdx.x;
    if (gid < 25600) { gsum[gid] = 0.f; return; }
    gid -= 25600;
    if (gid < 18432) {
        int j = gid & 7, kk = (gid >> 3) & 1, n = (gid >> 4) & 63, c = gid >> 10;
        int s = c >> 1, h = c & 1;
        int ci = 16 * h + 8 * kk + j;
        w2f[gid] = bfc(w2[(s * 32 + ci) * 64 + n]);
        return;
    }
    gid -= 18432;
    if (gid < 512) {
        int j = gid & 7, ll = gid >> 3;
        int k = 8 * (ll >> 5) + j;
        int r = k >> 2, c4 = k & 3, co = ll & 31;
        w1f[gid] = (r < 3 && c4 < 3) ? bfc(w1[(r * 3 + c4) * 32 + co])
                                     : (unsigned short)0;
        return;
    }
    gid -= 512;
    if (gid < 1600) {
        const float4* a = (const float4*)(fc1w + gid * 512);
        const float4* bq = (const float4*)fc2w;
        float s = 0.f;
        for (int q = 0; q < 128; ++q) {
            float4 av = a[q], bv = bq[q];
            s += av.x * bv.x + av.y * bv.y + av.z * bv.z + av.w * bv.w;
        }
        v[gid] = s;
    }
}

// ---------------------------------------------------------------------------
// Fused: 4 waves/block (2M x 2N split), IPB images, 32x32x16 MFMA both convs,
// quad-mapped M. Wave (mw,nw): conv2 M-tiles {mw, mw+2} x N-half nw
// (bb[18] = 72 VGPR, one live acc chain -> ~130 VGPR, no spill).
// conv1: dual shifted bf16 image copies, uniform non-divergent reads.
// sp2 slot-XOR swizzle (write & read sides). 1 raw s_barrier per image,
// lgkmcnt-only drain; dbuf simg+sp2; register prefetch of next image.
// ---------------------------------------------------------------------------
__global__ __launch_bounds__(256) void fused(
        const float* __restrict__ x,
        const unsigned short* __restrict__ w1f, const float* __restrict__ b1,
        const unsigned short* __restrict__ w2f, const float* __restrict__ b2,
        float* __restrict__ gsum)
{
    __shared__ __align__(16) unsigned short simgb[2][1568]; // [dbuf][copy0|copy1]
    __shared__ __align__(16) unsigned short sp2[2][5760];   // [dbuf][quad144][40ch swz]

    const int tid = threadIdx.x;
    const int wv = tid >> 6;
    const int l = tid & 63;
    const int l31 = l & 31, lh = l >> 5;
    const int mw = wv & 1, nw = wv >> 1;

    // conv1 B-frag
    const short8 wb1 = *(const short8*)(w1f + l * 8);
    const float cb1 = b1[l31];

    // conv2 B-frags: one N-half (72 VGPR)
    short8 bb[18];
    #pragma unroll
    for (int c = 0; c < 18; ++c)
        bb[c] = *(const short8*)(w2f + ((c * 64 + 32 * nw + l31) * 2 + lh) * 8);
    const float cb2 = b2[32 * nw + l31];

    // conv2 A base positions for this wave's two M-tiles (mw, mw+2)
    int posb[2];
    #pragma unroll
    for (int mti = 0; mti < 2; ++mti) {
        int m2 = 32 * (2 * mti + mw) + l31; if (m2 > 99) m2 = 99;
        const int q2i = m2 >> 2, idx2 = m2 & 3;
        posb[mti] = (2 * (q2i / 5) + (idx2 >> 1)) * 12 + 2 * (q2i % 5) + (idx2 & 1);
    }

    float pacc[2][4];
    #pragma unroll
    for (int a = 0; a < 2; ++a)
        #pragma unroll
        for (int b = 0; b < 4; ++b) pacc[a][b] = 0.f;

    const int imgbase = blockIdx.x * IPB;
    const float* xbase = x + (size_t)imgbase * 784;

    // prologue: pack image 0 into simgb[0] (copy0 + 1-px-shifted copy1)
    if (tid < 98) {
        const float4* xg = (const float4*)xbase;
        float4 A = xg[2 * tid], B = xg[2 * tid + 1];
        float sc = xbase[(8 * tid + 8 < 784) ? 8 * tid + 8 : 783];
        *(u32x4*)(&simgb[0][8 * tid]) =
            (u32x4){pk2(A.x, A.y), pk2(A.z, A.w), pk2(B.x, B.y), pk2(B.z, B.w)};
        *(u32x4*)(&simgb[0][784 + 8 * tid]) =
            (u32x4){pk2(A.y, A.z), pk2(A.w, B.x), pk2(B.y, B.z), pk2(B.w, sc)};
    }
    asm volatile("s_waitcnt lgkmcnt(0)" ::: "memory");
    __builtin_amdgcn_s_barrier();

    for (int ii = 0; ii < IPB; ++ii) {
        const int cur = ii & 1;
        const unsigned short* simgc = simgb[cur];
        unsigned short* sp2c = sp2[cur];

        // issue next-image global loads early (HBM latency hides under conv1)
        float4 A4, B4; float sc = 0.f;
        const bool pf = (ii + 1 < IPB) && (tid < 98);
        if (pf) {
            const float4* xn = (const float4*)(xbase + (ii + 1) * 784);
            A4 = xn[2 * tid]; B4 = xn[2 * tid + 1];
            sc = xbase[(ii + 1) * 784 + ((8 * tid + 8 < 784) ? 8 * tid + 8 : 783)];
        }

        // ---- conv1: tiles t = 4*t9 + wv, uniform read pattern all lanes ----
        #pragma unroll
        for (int t9 = 0; t9 < 5; ++t9) {
            const int t = 4 * t9 + wv;
            if (t < 18) {
                const int qd = 8 * t + (l31 >> 2);
                const int idx1 = l & 3;
                const int pr = qd / 12, pc = qd % 12;
                const int rr = 2 * pr + (idx1 >> 1), ccc = 2 * pc + (idx1 & 1);
                const int s = ccc & 1;
                // lh==1 lanes shift +2 rows; their k=11..15 weight slots are 0.
                const int halfoff = s * 784 + rr * 28 + (ccc - s) + 56 * lh;
                const unsigned* bp = (const unsigned*)((const char*)simgc + 2 * halfoff);
                const unsigned d0 = bp[0], d1 = bp[1], d2 = bp[14], d3 = bp[15];
                const short8 af = __builtin_bit_cast(short8, (u32x4){d0, d1, d2, d3});
                f32x16 cc;
                #pragma unroll
                for (int z = 0; z < 16; ++z) cc[z] = cb1;
                cc = __builtin_amdgcn_mfma_f32_32x32x16_bf16(af, wb1, cc, 0, 0, 0);
                const int key1 = t & 3;
                const int choff = (((l31 >> 3) ^ key1) << 3) + (l31 & 7);
                #pragma unroll
                for (int rq = 0; rq < 4; ++rq) {
                    float p = fmaxf(fmaxf(cc[4 * rq], cc[4 * rq + 1]),
                                    fmaxf(cc[4 * rq + 2], cc[4 * rq + 3]));
                    p = fmaxf(p, 0.f);
                    sp2c[(8 * t + 2 * rq + lh) * 40 + choff] = bfc(p);
                }
            }
        }

        // pack prefetched image into the other buffer
        if (pf) {
            unsigned short* dst = simgb[cur ^ 1];
            *(u32x4*)(&dst[8 * tid]) =
                (u32x4){pk2(A4.x, A4.y), pk2(A4.z, A4.w), pk2(B4.x, B4.y), pk2(B4.z, B4.w)};
            *(u32x4*)(&dst[784 + 8 * tid]) =
                (u32x4){pk2(A4.y, A4.z), pk2(A4.w, B4.x), pk2(B4.y, B4.z), pk2(B4.w, sc)};
        }
        asm volatile("s_waitcnt lgkmcnt(0)" ::: "memory");
        __builtin_amdgcn_s_barrier();

        // ---- conv2: 2 M-tiles sequentially, one N-half, swizzled A reads ----
        #pragma unroll
        for (int mti = 0; mti < 2; ++mti) {
            f32x16 acc;
            #pragma unroll
            for (int z = 0; z < 16; ++z) acc[z] = cb2;
            __builtin_amdgcn_s_setprio(1);
            #pragma unroll
            for (int s = 0; s < 9; ++s) {
                const int posp = posb[mti] + (s / 3) * 12 + (s % 3);
                const int key = (posp >> 3) & 3;
                const char* base = (const char*)sp2c + posp * 80;
                const short8 af0 = *(const short8*)(base + ((lh ^ key) << 4));
                const short8 af1 = *(const short8*)(base + (((2 + lh) ^ key) << 4));
                acc = __builtin_amdgcn_mfma_f32_32x32x16_bf16(af0, bb[2 * s],     acc, 0, 0, 0);
                acc = __builtin_amdgcn_mfma_f32_32x32x16_bf16(af1, bb[2 * s + 1], acc, 0, 0, 0);
            }
            __builtin_amdgcn_s_setprio(0);
            #pragma unroll
            for (int rq = 0; rq < 4; ++rq) {
                float p = fmaxf(fmaxf(acc[4 * rq], acc[4 * rq + 1]),
                                fmaxf(acc[4 * rq + 2], acc[4 * rq + 3]));
                pacc[mti][rq] += fmaxf(p, 0.f);
            }
        }
    }

    // one atomic per (quad, channel) per block; mt==3 keeps only rq0/lh0 (q2==24)
    const int grp = imgbase >> 9;
    float* gs = gsum + grp * EMB;
    #pragma unroll
    for (int mti = 0; mti < 2; ++mti) {
        const int mt = 2 * mti + mw;
        #pragma unroll
        for (int rq = 0; rq < 4; ++rq) {
            if (mt < 3 || (rq == 0 && lh == 0)) {
                const int q2 = 8 * mt + 2 * rq + lh;
                atomicAdd(&gs[q2 * 64 + 32 * nw + l31], pacc[mti][rq]);
            }
        }
    }
}

// mean/512 -> max over 16 groups -> dot v -> + fc1b.fc2w + fc2b -> sigmoid
__global__ __launch_bounds__(256) void head(
        const float* __restrict__ gsum, const float* __restrict__ v,
        const float* __restrict__ fc1b, const float* __restrict__ fc2w,
        const float* __restrict__ fc2b, float* __restrict__ out)
{
    __shared__ float sred[256];
    const int tid = threadIdx.x;
    float partial = 0.f;
    const float4* g4 = (const float4*)gsum;
    const float4* v4 = (const float4*)v;
    for (int i = tid; i < 400; i += 256) {
        float4 m = g4[i];
        #pragma unroll
        for (int gg = 1; gg < GROUPS; ++gg) {
            float4 t = g4[gg * 400 + i];
            m.x = fmaxf(m.x, t.x); m.y = fmaxf(m.y, t.y);
            m.z = fmaxf(m.z, t.z); m.w = fmaxf(m.w, t.w);
        }
        float4 vv = v4[i];
        partial += m.x * vv.x + m.y * vv.y + m.z * vv.z + m.w * vv.w;
    }
    partial *= (1.f / 512.f);
    partial += fc1b[tid] * fc2w[tid] + fc1b[tid + 256] * fc2w[tid + 256];
    sred[tid] = partial;
    __syncthreads();
    for (int s = 128; s > 0; s >>= 1) {
        if (tid < s) sred[tid] += sred[tid + s];
        __syncthreads();
    }
    if (tid == 0) out[0] = 1.f / (1.f + expf(-(sred[0] + fc2b[0])));
}

extern "C" void kernel_launch(void* const* d_in, const int* in_sizes, int n_in,
                              void* d_out, int out_size, void* d_ws, size_t ws_size,
                              hipStream_t stream)
{
    const float* x    = (const float*)d_in[0];
    const float* w1   = (const float*)d_in[1];
    const float* b1   = (const float*)d_in[2];
    const float* w2   = (const float*)d_in[3];
    const float* b2   = (const float*)d_in[4];
    const float* fc1w = (const float*)d_in[5];
    const float* fc1b = (const float*)d_in[6];
    const float* fc2w = (const float*)d_in[7];
    const float* fc2b = (const float*)d_in[8];

    float* gsum = (float*)d_ws;
    unsigned short* w2f = (unsigned short*)((char*)d_ws + WS_W2F);
    unsigned short* w1f = (unsigned short*)((char*)d_ws + WS_W1F);
    float* v = (float*)((char*)d_ws + WS_V);

    prep<<<181, 256, 0, stream>>>(w1, w2, fc1w, fc2w, gsum, w1f, w2f, v);
    fused<<<N_IMG / IPB, 256, 0, stream>>>(x, w1f, b1, w2f, b2, gsum);
    head<<<1, 256, 0, stream>>>(gsum, v, fc1b, fc2w, fc2b, (float*)d_out);
}